// Round 1
// baseline (883.224 us; speedup 1.0000x reference)
//
#include <hip/hip_runtime.h>
#include <math.h>

// RGAT_Decoder: B=32,T=500,D=128,K=64,H=8. f32 end-to-end baseline.
// ws layout (floats): h_ws[H][B][T][K] | src_ws[H][B][T] | tar_ws[H][B][T]
//                     | msgs[B][T][K] | pred[B][T][K] | dargs[B][1000]
// total = 10,528,000 f32 = 42.1 MB

#define BB 32
#define TT 500
#define DD 128
#define KK 64
#define HH 8
#define NEGV -9.0e15f

// ---------------- Kernel 1: h = einsum('btd,hdk->hbtk') + src/tar dots ----
__global__ __launch_bounds__(256) void k1_h(
        const float* __restrict__ inputs, const float* __restrict__ linear,
        const float* __restrict__ att_src, const float* __restrict__ att_tar,
        float* __restrict__ h_ws, float* __restrict__ src_ws, float* __restrict__ tar_ws) {
    __shared__ __align__(16) float lin_s[DD * KK];   // [d][k]
    __shared__ __align__(16) float inp_s[64 * DD];   // [tl][d]
    __shared__ float asrc_s[KK], atar_s[KK];
    const int t0 = blockIdx.x * 64;
    const int b  = blockIdx.y;
    const int hh = blockIdx.z;
    const int tid = threadIdx.x;
    const int k = tid & 63, tq = tid >> 6;

    for (int e = tid; e < DD * KK; e += 256) lin_s[e] = linear[hh * DD * KK + e];
    for (int e = tid; e < 64 * DD; e += 256) {
        int row = e >> 7, d = e & 127;
        int t = t0 + row;
        inp_s[e] = (t < TT) ? inputs[(b * TT + t) * DD + d] : 0.f;
    }
    if (tid < KK) { asrc_s[tid] = att_src[hh * KK + tid]; atar_s[tid] = att_tar[hh * KK + tid]; }
    __syncthreads();

    float acc[16];
#pragma unroll
    for (int i = 0; i < 16; ++i) acc[i] = 0.f;

    for (int d4 = 0; d4 < DD / 4; ++d4) {
        float l0 = lin_s[(d4 * 4 + 0) * KK + k];
        float l1 = lin_s[(d4 * 4 + 1) * KK + k];
        float l2 = lin_s[(d4 * 4 + 2) * KK + k];
        float l3 = lin_s[(d4 * 4 + 3) * KK + k];
#pragma unroll
        for (int i = 0; i < 16; ++i) {
            const float4 iv = *(const float4*)&inp_s[(tq * 16 + i) * DD + d4 * 4];
            acc[i] += iv.x * l0 + iv.y * l1 + iv.z * l2 + iv.w * l3;
        }
    }
    const long hb = (long)hh * BB + b;
#pragma unroll
    for (int i = 0; i < 16; ++i) {
        int t = t0 + tq * 16 + i;
        if (t < TT) h_ws[(hb * TT + t) * KK + k] = acc[i];
    }
    const float sv = asrc_s[k], tv = atar_s[k];
#pragma unroll
    for (int i = 0; i < 16; ++i) {
        float ss = acc[i] * sv, ts = acc[i] * tv;
#pragma unroll
        for (int o = 32; o > 0; o >>= 1) { ss += __shfl_xor(ss, o); ts += __shfl_xor(ts, o); }
        int t = t0 + tq * 16 + i;
        if (k == 0 && t < TT) { src_ws[hb * TT + t] = ss; tar_ws[hb * TT + t] = ts; }
    }
}

// ---------------- Kernel 2: masked softmax + att@h, mean over heads -------
__global__ __launch_bounds__(256) void k2_attn(
        const float* __restrict__ h_ws, const float* __restrict__ src_ws,
        const float* __restrict__ tar_ws, float* __restrict__ msgs) {
    __shared__ __align__(16) float hs[64 * KK];   // [srow][k]
    __shared__ __align__(16) float ps[64 * 64];   // [tl][ss]
    __shared__ float srcv[TT];
    __shared__ float tarv[64], m_row[64], d_row[64];
    const int t0 = blockIdx.x * 64;
    const int b  = blockIdx.y;
    const int hh = blockIdx.z;
    const int tid = threadIdx.x;
    const long hb = (long)hh * BB + b;
    const float* srcp = src_ws + hb * TT;
    const float* tarp = tar_ws + hb * TT;

    for (int e = tid; e < TT; e += 256) srcv[e] = srcp[e];
    if (tid < 64) tarv[tid] = (t0 + tid < TT) ? tarp[t0 + tid] : 0.f;
    __syncthreads();

    {   // phase 1: per-row max & sum of exp (4 threads per row)
        const int row = tid >> 2, j = tid & 3;
        const int t = t0 + row;
        const float tval = tarv[row];
        float mx = -3.0e38f;
        for (int s = j; s < TT; s += 4) {
            float x = tval + srcv[s];
            x = (x > 0.f) ? x : 0.2f * x;
            if (s == t) x = NEGV;
            mx = fmaxf(mx, x);
        }
        mx = fmaxf(mx, __shfl_xor(mx, 1));
        mx = fmaxf(mx, __shfl_xor(mx, 2));
        float sum = 0.f;
        for (int s = j; s < TT; s += 4) {
            float x = tval + srcv[s];
            x = (x > 0.f) ? x : 0.2f * x;
            if (s != t) sum += expf(x - mx);
        }
        sum += __shfl_xor(sum, 1);
        sum += __shfl_xor(sum, 2);
        if (j == 0) { m_row[row] = mx; d_row[row] = 1.f / sum; }
    }
    __syncthreads();

    const int k = tid & 63, tq = tid >> 6;
    float acc[16];
#pragma unroll
    for (int i = 0; i < 16; ++i) acc[i] = 0.f;

    for (int s0 = 0; s0 < 512; s0 += 64) {
        for (int e = tid; e < 64 * KK; e += 256) {
            int srow = e >> 6, kk = e & 63;
            int s = s0 + srow;
            hs[e] = (s < TT) ? h_ws[(hb * TT + s) * KK + kk] : 0.f;
        }
        for (int e = tid; e < 64 * 64; e += 256) {
            int tl = e >> 6, ssl = e & 63;
            int s = s0 + ssl, t = t0 + tl;
            float p = 0.f;
            if (s < TT && t < TT && s != t) {
                float x = tarv[tl] + srcv[s];
                x = (x > 0.f) ? x : 0.2f * x;
                p = expf(x - m_row[tl]) * d_row[tl];
            }
            ps[e] = p;
        }
        __syncthreads();
        for (int s4 = 0; s4 < 16; ++s4) {
            float h0 = hs[(s4 * 4 + 0) * KK + k];
            float h1 = hs[(s4 * 4 + 1) * KK + k];
            float h2 = hs[(s4 * 4 + 2) * KK + k];
            float h3 = hs[(s4 * 4 + 3) * KK + k];
#pragma unroll
            for (int i = 0; i < 16; ++i) {
                const float4 p4 = *(const float4*)&ps[(tq * 16 + i) * 64 + s4 * 4];
                acc[i] += p4.x * h0 + p4.y * h1 + p4.z * h2 + p4.w * h3;
            }
        }
        __syncthreads();
    }
#pragma unroll
    for (int i = 0; i < 16; ++i) {
        int t = t0 + tq * 16 + i;
        if (t < TT) atomicAdd(&msgs[(b * TT + t) * KK + k], acc[i] * (1.f / HH));
    }
}

// ---------------- Kernel 3: tanh + GRU gates + MLP, one wave per row ------
__global__ __launch_bounds__(256) void k3_gru(
        const float* __restrict__ inputs, const float* __restrict__ hidden,
        const float* __restrict__ bias,
        const float* __restrict__ W_hr, const float* __restrict__ W_hi, const float* __restrict__ W_hm,
        const float* __restrict__ W_ir, const float* __restrict__ b_ir,
        const float* __restrict__ W_ii, const float* __restrict__ b_ii,
        const float* __restrict__ W_in, const float* __restrict__ b_in,
        const float* __restrict__ W1, const float* __restrict__ b1,
        const float* __restrict__ W2, const float* __restrict__ b2,
        const float* __restrict__ msgs, float* __restrict__ out_hidden,
        float* __restrict__ pred) {
    const int tid = threadIdx.x;
    const int lane = tid & 63, w = tid >> 6;
    const int row = blockIdx.x * 4 + w;    // < 16000
    const float* inp = inputs + (long)row * DD;

    float mg = tanhf(msgs[(long)row * KK + lane] + bias[lane]);
    float hr = 0.f, hi = 0.f, hm = 0.f;
#pragma unroll 8
    for (int j = 0; j < KK; ++j) {
        float v = __shfl(mg, j);
        hr += v * W_hr[j * KK + lane];
        hi += v * W_hi[j * KK + lane];
        hm += v * W_hm[j * KK + lane];
    }
    float i0 = inp[lane], i1 = inp[64 + lane];
    float ir = 0.f, ii = 0.f, inn = 0.f;
#pragma unroll 8
    for (int j = 0; j < 64; ++j) {
        float v = __shfl(i0, j);
        ir  += v * W_ir[j * KK + lane];
        ii  += v * W_ii[j * KK + lane];
        inn += v * W_in[j * KK + lane];
    }
#pragma unroll 8
    for (int j = 0; j < 64; ++j) {
        float v = __shfl(i1, j);
        ir  += v * W_ir[(64 + j) * KK + lane];
        ii  += v * W_ii[(64 + j) * KK + lane];
        inn += v * W_in[(64 + j) * KK + lane];
    }
    float m  = 1.f / (1.f + expf(-(ir + b_ir[lane] + hr)));
    float ig = 1.f / (1.f + expf(-(ii + b_ii[lane] + hi)));
    float n  = tanhf(inn + b_in[lane] + m * hm);
    float hnew = ig * n + (1.f - ig) * hidden[(long)row * KK + lane];
    out_hidden[(long)row * KK + lane] = hnew;

    float a1 = 0.f;
#pragma unroll 8
    for (int j = 0; j < KK; ++j) a1 += __shfl(hnew, j) * W1[j * KK + lane];
    a1 = fmaxf(a1 + b1[lane], 0.f);
    float pr = 0.f;
#pragma unroll 8
    for (int j = 0; j < KK; ++j) pr += __shfl(a1, j) * W2[j * KK + lane];
    pred[(long)row * KK + lane] = pr + b2[lane];
}

// ---------------- Kernel 4: dargs = pred_resh @ proj_W (split-K) ----------
__global__ __launch_bounds__(256) void k4_proj(
        const float* __restrict__ pred, const float* __restrict__ proj_W,
        float* __restrict__ dargs) {
    __shared__ __align__(16) float ps[BB * 64];   // [b][rr]
    const int c = blockIdx.x * 256 + threadIdx.x;  // 0..1023
    const int r0 = blockIdx.y * 512;
    const int ntiles = (r0 + 512 <= 32000) ? 8 : (32000 - r0) / 64;
    float acc[BB];
#pragma unroll
    for (int b = 0; b < BB; ++b) acc[b] = 0.f;
    for (int tile = 0; tile < ntiles; ++tile) {
        const int rbase = r0 + tile * 64;
        __syncthreads();
        for (int e = threadIdx.x; e < BB * 64; e += 256) {
            int bb = e >> 6, rr = e & 63;
            ps[e] = pred[(long)bb * 32000 + rbase + rr];
        }
        __syncthreads();
        for (int r4 = 0; r4 < 16; ++r4) {
            float w0 = 0.f, w1 = 0.f, w2 = 0.f, w3 = 0.f;
            if (c < 1000) {
                const float* wp = proj_W + (long)(rbase + r4 * 4) * 1000 + c;
                w0 = wp[0]; w1 = wp[1000]; w2 = wp[2000]; w3 = wp[3000];
            }
#pragma unroll
            for (int b = 0; b < BB; ++b) {
                const float4 p4 = *(const float4*)&ps[b * 64 + r4 * 4];
                acc[b] += p4.x * w0 + p4.y * w1 + p4.z * w2 + p4.w * w3;
            }
        }
    }
    if (c < 1000) {
#pragma unroll
        for (int b = 0; b < BB; ++b) atomicAdd(&dargs[b * 1000 + c], acc[b]);
    }
}

// ---------------- Kernel 5: + proj_b, split loc / softplus(scale) ---------
__global__ void k5_final(const float* __restrict__ dargs, const float* __restrict__ proj_b,
                         float* __restrict__ out) {
    int idx = blockIdx.x * 256 + threadIdx.x;
    if (idx >= BB * 1000) return;
    int b = idx / 1000, c = idx % 1000;
    float v = dargs[idx] + proj_b[c];
    if (c < TT) {
        out[b * TT + c] = v;                                  // loc
    } else {
        float sp = fmaxf(v, 0.f) + log1pf(expf(-fabsf(v)));   // softplus
        out[BB * TT + b * TT + (c - TT)] = sp;                // scale
    }
}

extern "C" void kernel_launch(void* const* d_in, const int* in_sizes, int n_in,
                              void* d_out, int out_size, void* d_ws, size_t ws_size,
                              hipStream_t stream) {
    const float* inputs  = (const float*)d_in[0];
    const float* hidden  = (const float*)d_in[1];
    const float* linear  = (const float*)d_in[2];
    const float* bias    = (const float*)d_in[3];
    const float* att_src = (const float*)d_in[4];
    const float* att_tar = (const float*)d_in[5];
    const float* W_hr = (const float*)d_in[6];
    const float* W_hi = (const float*)d_in[7];
    const float* W_hm = (const float*)d_in[8];
    const float* W_ir = (const float*)d_in[9];
    const float* b_ir = (const float*)d_in[10];
    const float* W_ii = (const float*)d_in[11];
    const float* b_ii = (const float*)d_in[12];
    const float* W_in = (const float*)d_in[13];
    const float* b_in = (const float*)d_in[14];
    const float* W1 = (const float*)d_in[15];
    const float* b1 = (const float*)d_in[16];
    const float* W2 = (const float*)d_in[17];
    const float* b2 = (const float*)d_in[18];
    const float* proj_W = (const float*)d_in[19];
    const float* proj_b = (const float*)d_in[20];

    float* ws = (float*)d_ws;
    float* h_ws   = ws;                                     // H*B*T*K = 8,192,000
    float* src_ws = h_ws + (size_t)HH * BB * TT * KK;       // 128,000
    float* tar_ws = src_ws + (size_t)HH * BB * TT;          // 128,000
    float* msgs   = tar_ws + (size_t)HH * BB * TT;          // 1,024,000
    float* pred   = msgs + (size_t)BB * TT * KK;            // 1,024,000
    float* dargs  = pred + (size_t)BB * TT * KK;            // 32,000

    float* out = (float*)d_out;
    float* out_hidden = out + 2 * BB * TT;

    hipMemsetAsync(msgs, 0, (size_t)BB * TT * KK * sizeof(float), stream);
    hipMemsetAsync(dargs, 0, (size_t)BB * 1000 * sizeof(float), stream);

    k1_h<<<dim3(8, BB, HH), 256, 0, stream>>>(inputs, linear, att_src, att_tar,
                                              h_ws, src_ws, tar_ws);
    k2_attn<<<dim3(8, BB, HH), 256, 0, stream>>>(h_ws, src_ws, tar_ws, msgs);
    k3_gru<<<4000, 256, 0, stream>>>(inputs, hidden, bias, W_hr, W_hi, W_hm,
                                     W_ir, b_ir, W_ii, b_ii, W_in, b_in,
                                     W1, b1, W2, b2, msgs, out_hidden, pred);
    k4_proj<<<dim3(4, 63), 256, 0, stream>>>(pred, proj_W, dargs);
    k5_final<<<125, 256, 0, stream>>>(dargs, proj_b, out);
}

// Round 2
// 593.198 us; speedup vs baseline: 1.4889x; 1.4889x over previous
//
#include <hip/hip_runtime.h>
#include <hip/hip_bf16.h>
#include <math.h>

// RGAT_Decoder: B=32,T=500,D=128,K=64,H=8.
// ws layout: hT bf16 [H*B][64][512] (16.8MB) | src_ws[H*B*T] | tar_ws[H*B*T]
//            | msgs[B*T*K] | pred[B*T*K] | dargs[B*1000]   (f32)

#define BB 32
#define TT 500
#define DD 128
#define KK 64
#define HH 8

typedef short bf16x8 __attribute__((ext_vector_type(8)));
typedef float f32x16 __attribute__((ext_vector_type(16)));

static __device__ __forceinline__ unsigned short f2bf(float x) {
    __hip_bfloat16 h = __float2bfloat16(x);
    return *reinterpret_cast<unsigned short*>(&h);
}

// ---------------- Kernel 1: h = einsum('btd,hdk->hbtk') -> bf16 hT + src/tar dots
__global__ __launch_bounds__(256) void k1_h(
        const float* __restrict__ inputs, const float* __restrict__ linear,
        const float* __restrict__ att_src, const float* __restrict__ att_tar,
        unsigned short* __restrict__ hT, float* __restrict__ src_ws,
        float* __restrict__ tar_ws) {
    __shared__ __align__(16) float lin_s[DD * KK];   // [d][k]
    __shared__ __align__(16) float inp_s[64 * DD];   // [tl][d]
    __shared__ float asrc_s[KK], atar_s[KK];
    const int t0 = blockIdx.x * 64;
    const int b  = blockIdx.y;
    const int hh = blockIdx.z;
    const int tid = threadIdx.x;
    const int k = tid & 63, tq = tid >> 6;

    for (int e = tid; e < DD * KK; e += 256) lin_s[e] = linear[hh * DD * KK + e];
    for (int e = tid; e < 64 * DD; e += 256) {
        int row = e >> 7, d = e & 127;
        int t = t0 + row;
        inp_s[e] = (t < TT) ? inputs[(b * TT + t) * DD + d] : 0.f;
    }
    if (tid < KK) { asrc_s[tid] = att_src[hh * KK + tid]; atar_s[tid] = att_tar[hh * KK + tid]; }
    __syncthreads();

    float acc[16];
#pragma unroll
    for (int i = 0; i < 16; ++i) acc[i] = 0.f;

    for (int d4 = 0; d4 < DD / 4; ++d4) {
        float l0 = lin_s[(d4 * 4 + 0) * KK + k];
        float l1 = lin_s[(d4 * 4 + 1) * KK + k];
        float l2 = lin_s[(d4 * 4 + 2) * KK + k];
        float l3 = lin_s[(d4 * 4 + 3) * KK + k];
#pragma unroll
        for (int i = 0; i < 16; ++i) {
            const float4 iv = *(const float4*)&inp_s[(tq * 16 + i) * DD + d4 * 4];
            acc[i] += iv.x * l0 + iv.y * l1 + iv.z * l2 + iv.w * l3;
        }
    }
    const long hb = (long)hh * BB + b;
    // transposed bf16 store: hT[hb][k][t0 + tq*16 .. +16]  (rows t>=500 are exact 0)
    {
        union { unsigned short u[16]; int4 v[2]; } pk;
#pragma unroll
        for (int i = 0; i < 16; ++i) pk.u[i] = f2bf(acc[i]);
        unsigned short* hp = hT + hb * (64L * 512) + (long)k * 512 + t0 + tq * 16;
        *(int4*)(hp)     = pk.v[0];
        *(int4*)(hp + 8) = pk.v[1];
    }
    const float sv = asrc_s[k], tv = atar_s[k];
#pragma unroll
    for (int i = 0; i < 16; ++i) {
        float ss = acc[i] * sv, ts = acc[i] * tv;
#pragma unroll
        for (int o = 32; o > 0; o >>= 1) { ss += __shfl_xor(ss, o); ts += __shfl_xor(ts, o); }
        int t = t0 + tq * 16 + i;
        if (k == 0 && t < TT) { src_ws[hb * TT + t] = ss; tar_ws[hb * TT + t] = ts; }
    }
}

// ---------------- Kernel 2: masked softmax + att@h via bf16 MFMA, mean over heads
__global__ __launch_bounds__(256) void k2_attn(
        const unsigned short* __restrict__ hT, const float* __restrict__ src_ws,
        const float* __restrict__ tar_ws, float* __restrict__ msgs) {
    __shared__ float srcv[512];
    __shared__ float red[4];
    __shared__ float partial[4][64];
    __shared__ float drow[64];
    __shared__ __align__(16) unsigned short es[64 * 128];  // swizzled [t][s] bf16
    __shared__ __align__(16) unsigned short hs[64 * 128];  // swizzled [k][s] bf16

    const int t0 = blockIdx.x * 64;
    const int b  = blockIdx.y;
    const int hh = blockIdx.z;
    const int tid = threadIdx.x;
    const long hb = (long)hh * BB + b;
    const float* srcp = src_ws + hb * TT;

    for (int e = tid; e < 512; e += 256) srcv[e] = (e < TT) ? srcp[e] : -3.0e38f;
    __syncthreads();
    float sm = -3.0e38f;
    for (int e = tid; e < 512; e += 256) sm = fmaxf(sm, srcv[e]);
#pragma unroll
    for (int o = 32; o > 0; o >>= 1) sm = fmaxf(sm, __shfl_xor(sm, o));
    if ((tid & 63) == 0) red[tid >> 6] = sm;
    __syncthreads();
    const float Smax = fmaxf(fmaxf(red[0], red[1]), fmaxf(red[2], red[3]));

    const int tl = tid & 63, g = tid >> 6;
    const int tglob = t0 + tl;
    const float tv = (tglob < TT) ? tar_ws[hb * TT + tglob] : 0.f;
    // exact row max: leaky_relu is monotonic, so m_t = leaky(tar_t + max_s src_s)
    const float xm = tv + Smax;
    const float ml = fmaxf(xm, 0.2f * xm);

    const unsigned short* hTg = hT + hb * (64L * 512);
    const int lane = tid & 63, wid = tid >> 6;
    const int wr = wid >> 1, wc = wid & 1;
    f32x16 acc;
#pragma unroll
    for (int r = 0; r < 16; ++r) acc[r] = 0.f;

    float lsum = 0.f;
    for (int s0 = 0; s0 < 512; s0 += 128) {
        // stage h tile [64 k-rows][128 s] bf16, XOR-swizzled
#pragma unroll
        for (int p = 0; p < 4; ++p) {
            const int r = p * 16 + (tid >> 4), c = tid & 15;
            const int4 hv = *(const int4*)(hTg + (long)r * 512 + s0 + c * 8);
            const int wa = (r * 256 + c * 16) ^ ((r & 7) << 4);
            *(int4*)((char*)hs + wa) = hv;
        }
        // generate unnormalized e tile [64 t][128 s] bf16, XOR-swizzled; fuse row-sum
#pragma unroll
        for (int i = 0; i < 4; ++i) {
            const int sl = g * 8 + i * 32;
            const int sg = s0 + sl;
            union { unsigned short u[8]; int4 v; } pk;
#pragma unroll
            for (int j = 0; j < 8; ++j) {
                float x = tv + srcv[sg + j];
                float l = fmaxf(x, 0.2f * x);     // leaky_relu(x,0.2) == max(x,0.2x)
                float e = __expf(l - ml);         // s>=500: srcv=-3e38 -> e=0
                if (sg + j == tglob) e = 0.f;     // diagonal mask
                lsum += e;
                pk.u[j] = f2bf(e);
            }
            const int wa = (tl * 256 + sl * 2) ^ ((tl & 7) << 4);
            *(int4*)((char*)es + wa) = pk.v;
        }
        __syncthreads();
        // 32x32x16 bf16 MFMA: wave (wr,wc) owns out[wr*32+32][wc*32+32]
#pragma unroll
        for (int st = 0; st < 8; ++st) {
            const int sA = st * 16 + (lane >> 5) * 8;
            const int arow = wr * 32 + (lane & 31);
            const int brow = wc * 32 + (lane & 31);
            bf16x8 av = *(bf16x8*)((char*)es + ((arow * 256 + sA * 2) ^ ((arow & 7) << 4)));
            bf16x8 bv = *(bf16x8*)((char*)hs + ((brow * 256 + sA * 2) ^ ((brow & 7) << 4)));
            acc = __builtin_amdgcn_mfma_f32_32x32x16_bf16(av, bv, acc, 0, 0, 0);
        }
        __syncthreads();
    }
    partial[g][tl] = lsum;
    __syncthreads();
    if (tid < 64) {
        float s = partial[0][tid] + partial[1][tid] + partial[2][tid] + partial[3][tid];
        drow[tid] = 1.f / s;
    }
    __syncthreads();
#pragma unroll
    for (int r = 0; r < 16; ++r) {
        const int row = wr * 32 + (r & 3) + 8 * (r >> 2) + 4 * (lane >> 5);
        const int t = t0 + row;
        if (t < TT) {
            const float v = acc[r] * drow[row] * 0.125f;
            atomicAdd(&msgs[((long)b * TT + t) * KK + (wc * 32 + (lane & 31))], v);
        }
    }
}

// ---------------- Kernel 3: tanh + GRU gates + MLP, one wave per row ------
__global__ __launch_bounds__(256) void k3_gru(
        const float* __restrict__ inputs, const float* __restrict__ hidden,
        const float* __restrict__ bias,
        const float* __restrict__ W_hr, const float* __restrict__ W_hi, const float* __restrict__ W_hm,
        const float* __restrict__ W_ir, const float* __restrict__ b_ir,
        const float* __restrict__ W_ii, const float* __restrict__ b_ii,
        const float* __restrict__ W_in, const float* __restrict__ b_in,
        const float* __restrict__ W1, const float* __restrict__ b1,
        const float* __restrict__ W2, const float* __restrict__ b2,
        const float* __restrict__ msgs, float* __restrict__ out_hidden,
        float* __restrict__ pred) {
    const int tid = threadIdx.x;
    const int lane = tid & 63, w = tid >> 6;
    const int row = blockIdx.x * 4 + w;    // < 16000
    const float* inp = inputs + (long)row * DD;

    float mg = tanhf(msgs[(long)row * KK + lane] + bias[lane]);
    float hr = 0.f, hi = 0.f, hm = 0.f;
#pragma unroll 8
    for (int j = 0; j < KK; ++j) {
        float v = __shfl(mg, j);
        hr += v * W_hr[j * KK + lane];
        hi += v * W_hi[j * KK + lane];
        hm += v * W_hm[j * KK + lane];
    }
    float i0 = inp[lane], i1 = inp[64 + lane];
    float ir = 0.f, ii = 0.f, inn = 0.f;
#pragma unroll 8
    for (int j = 0; j < 64; ++j) {
        float v = __shfl(i0, j);
        ir  += v * W_ir[j * KK + lane];
        ii  += v * W_ii[j * KK + lane];
        inn += v * W_in[j * KK + lane];
    }
#pragma unroll 8
    for (int j = 0; j < 64; ++j) {
        float v = __shfl(i1, j);
        ir  += v * W_ir[(64 + j) * KK + lane];
        ii  += v * W_ii[(64 + j) * KK + lane];
        inn += v * W_in[(64 + j) * KK + lane];
    }
    float m  = 1.f / (1.f + expf(-(ir + b_ir[lane] + hr)));
    float ig = 1.f / (1.f + expf(-(ii + b_ii[lane] + hi)));
    float n  = tanhf(inn + b_in[lane] + m * hm);
    float hnew = ig * n + (1.f - ig) * hidden[(long)row * KK + lane];
    out_hidden[(long)row * KK + lane] = hnew;

    float a1 = 0.f;
#pragma unroll 8
    for (int j = 0; j < KK; ++j) a1 += __shfl(hnew, j) * W1[j * KK + lane];
    a1 = fmaxf(a1 + b1[lane], 0.f);
    float pr = 0.f;
#pragma unroll 8
    for (int j = 0; j < KK; ++j) pr += __shfl(a1, j) * W2[j * KK + lane];
    pred[(long)row * KK + lane] = pr + b2[lane];
}

// ---------------- Kernel 4: dargs = pred_resh @ proj_W (split-K) ----------
__global__ __launch_bounds__(256) void k4_proj(
        const float* __restrict__ pred, const float* __restrict__ proj_W,
        float* __restrict__ dargs) {
    __shared__ __align__(16) float ps[BB * 64];   // [b][rr]
    const int c = blockIdx.x * 256 + threadIdx.x;  // 0..1023
    const int r0 = blockIdx.y * 512;
    const int ntiles = (r0 + 512 <= 32000) ? 8 : (32000 - r0) / 64;
    float acc[BB];
#pragma unroll
    for (int b = 0; b < BB; ++b) acc[b] = 0.f;
    for (int tile = 0; tile < ntiles; ++tile) {
        const int rbase = r0 + tile * 64;
        __syncthreads();
        for (int e = threadIdx.x; e < BB * 64; e += 256) {
            int bb = e >> 6, rr = e & 63;
            ps[e] = pred[(long)bb * 32000 + rbase + rr];
        }
        __syncthreads();
        for (int r4 = 0; r4 < 16; ++r4) {
            float w0 = 0.f, w1 = 0.f, w2 = 0.f, w3 = 0.f;
            if (c < 1000) {
                const float* wp = proj_W + (long)(rbase + r4 * 4) * 1000 + c;
                w0 = wp[0]; w1 = wp[1000]; w2 = wp[2000]; w3 = wp[3000];
            }
#pragma unroll
            for (int b = 0; b < BB; ++b) {
                const float4 p4 = *(const float4*)&ps[b * 64 + r4 * 4];
                acc[b] += p4.x * w0 + p4.y * w1 + p4.z * w2 + p4.w * w3;
            }
        }
    }
    if (c < 1000) {
#pragma unroll
        for (int b = 0; b < BB; ++b) atomicAdd(&dargs[b * 1000 + c], acc[b]);
    }
}

// ---------------- Kernel 5: + proj_b, split loc / softplus(scale) ---------
__global__ void k5_final(const float* __restrict__ dargs, const float* __restrict__ proj_b,
                         float* __restrict__ out) {
    int idx = blockIdx.x * 256 + threadIdx.x;
    if (idx >= BB * 1000) return;
    int b = idx / 1000, c = idx % 1000;
    float v = dargs[idx] + proj_b[c];
    if (c < TT) {
        out[b * TT + c] = v;                                  // loc
    } else {
        float sp = fmaxf(v, 0.f) + log1pf(expf(-fabsf(v)));   // softplus
        out[BB * TT + b * TT + (c - TT)] = sp;                // scale
    }
}

extern "C" void kernel_launch(void* const* d_in, const int* in_sizes, int n_in,
                              void* d_out, int out_size, void* d_ws, size_t ws_size,
                              hipStream_t stream) {
    const float* inputs  = (const float*)d_in[0];
    const float* hidden  = (const float*)d_in[1];
    const float* linear  = (const float*)d_in[2];
    const float* bias    = (const float*)d_in[3];
    const float* att_src = (const float*)d_in[4];
    const float* att_tar = (const float*)d_in[5];
    const float* W_hr = (const float*)d_in[6];
    const float* W_hi = (const float*)d_in[7];
    const float* W_hm = (const float*)d_in[8];
    const float* W_ir = (const float*)d_in[9];
    const float* b_ir = (const float*)d_in[10];
    const float* W_ii = (const float*)d_in[11];
    const float* b_ii = (const float*)d_in[12];
    const float* W_in = (const float*)d_in[13];
    const float* b_in = (const float*)d_in[14];
    const float* W1 = (const float*)d_in[15];
    const float* b1 = (const float*)d_in[16];
    const float* W2 = (const float*)d_in[17];
    const float* b2 = (const float*)d_in[18];
    const float* proj_W = (const float*)d_in[19];
    const float* proj_b = (const float*)d_in[20];

    unsigned short* hT = (unsigned short*)d_ws;             // H*B*64*512 bf16 = 8,388,608
    float* fbase  = (float*)(hT + 8388608);
    float* src_ws = fbase;                                  // 128,000
    float* tar_ws = src_ws + (size_t)HH * BB * TT;          // 128,000
    float* msgs   = tar_ws + (size_t)HH * BB * TT;          // 1,024,000
    float* pred   = msgs + (size_t)BB * TT * KK;            // 1,024,000
    float* dargs  = pred + (size_t)BB * TT * KK;            // 32,000

    float* out = (float*)d_out;
    float* out_hidden = out + 2 * BB * TT;

    hipMemsetAsync(msgs, 0, (size_t)BB * TT * KK * sizeof(float), stream);
    hipMemsetAsync(dargs, 0, (size_t)BB * 1000 * sizeof(float), stream);

    k1_h<<<dim3(8, BB, HH), 256, 0, stream>>>(inputs, linear, att_src, att_tar,
                                              hT, src_ws, tar_ws);
    k2_attn<<<dim3(8, BB, HH), 256, 0, stream>>>(hT, src_ws, tar_ws, msgs);
    k3_gru<<<4000, 256, 0, stream>>>(inputs, hidden, bias, W_hr, W_hi, W_hm,
                                     W_ir, b_ir, W_ii, b_ii, W_in, b_in,
                                     W1, b1, W2, b2, msgs, out_hidden, pred);
    k4_proj<<<dim3(4, 63), 256, 0, stream>>>(pred, proj_W, dargs);
    k5_final<<<125, 256, 0, stream>>>(dargs, proj_b, out);
}

// Round 5
// 538.039 us; speedup vs baseline: 1.6416x; 1.1025x over previous
//
#include <hip/hip_runtime.h>
#include <hip/hip_bf16.h>
#include <math.h>

// RGAT_Decoder: B=32,T=500,D=128,K=64,H=8.
// ws layout: hT bf16 [H*B][64][512] (16.8MB) | src_ws[H*B*T] | tar_ws[H*B*T]
//            | msgs[B*T*K] | pred[B*T*K] | dargs[B*1000]   (f32)

#define BB 32
#define TT 500
#define DD 128
#define KK 64
#define HH 8

typedef short bf16x8 __attribute__((ext_vector_type(8)));
typedef float f32x16 __attribute__((ext_vector_type(16)));

static __device__ __forceinline__ unsigned short f2bf(float x) {
    __hip_bfloat16 h = __float2bfloat16(x);
    return *reinterpret_cast<unsigned short*>(&h);
}

// ---------------- Kernel 1: h = einsum('btd,hdk->hbtk') -> bf16 hT + src/tar dots
__global__ __launch_bounds__(256) void k1_h(
        const float* __restrict__ inputs, const float* __restrict__ linear,
        const float* __restrict__ att_src, const float* __restrict__ att_tar,
        unsigned short* __restrict__ hT, float* __restrict__ src_ws,
        float* __restrict__ tar_ws) {
    __shared__ __align__(16) float lin_s[DD * KK];   // [d][k]
    __shared__ __align__(16) float inp_s[64 * DD];   // [tl][d]
    __shared__ float asrc_s[KK], atar_s[KK];
    const int t0 = blockIdx.x * 64;
    const int b  = blockIdx.y;
    const int hh = blockIdx.z;
    const int tid = threadIdx.x;
    const int k = tid & 63, tq = tid >> 6;

    for (int e = tid; e < DD * KK; e += 256) lin_s[e] = linear[hh * DD * KK + e];
    for (int e = tid; e < 64 * DD; e += 256) {
        int row = e >> 7, d = e & 127;
        int t = t0 + row;
        inp_s[e] = (t < TT) ? inputs[(b * TT + t) * DD + d] : 0.f;
    }
    if (tid < KK) { asrc_s[tid] = att_src[hh * KK + tid]; atar_s[tid] = att_tar[hh * KK + tid]; }
    __syncthreads();

    float acc[16];
#pragma unroll
    for (int i = 0; i < 16; ++i) acc[i] = 0.f;

    for (int d4 = 0; d4 < DD / 4; ++d4) {
        float l0 = lin_s[(d4 * 4 + 0) * KK + k];
        float l1 = lin_s[(d4 * 4 + 1) * KK + k];
        float l2 = lin_s[(d4 * 4 + 2) * KK + k];
        float l3 = lin_s[(d4 * 4 + 3) * KK + k];
#pragma unroll
        for (int i = 0; i < 16; ++i) {
            const float4 iv = *(const float4*)&inp_s[(tq * 16 + i) * DD + d4 * 4];
            acc[i] += iv.x * l0 + iv.y * l1 + iv.z * l2 + iv.w * l3;
        }
    }
    const long hb = (long)hh * BB + b;
    // transposed bf16 store: hT[hb][k][t0 + tq*16 .. +16]  (rows t>=500 are exact 0)
    {
        union { unsigned short u[16]; int4 v[2]; } pk;
#pragma unroll
        for (int i = 0; i < 16; ++i) pk.u[i] = f2bf(acc[i]);
        unsigned short* hp = hT + hb * (64L * 512) + (long)k * 512 + t0 + tq * 16;
        *(int4*)(hp)     = pk.v[0];
        *(int4*)(hp + 8) = pk.v[1];
    }
    const float sv = asrc_s[k], tv = atar_s[k];
#pragma unroll
    for (int i = 0; i < 16; ++i) {
        float ss = acc[i] * sv, ts = acc[i] * tv;
#pragma unroll
        for (int o = 32; o > 0; o >>= 1) { ss += __shfl_xor(ss, o); ts += __shfl_xor(ts, o); }
        int t = t0 + tq * 16 + i;
        if (k == 0 && t < TT) { src_ws[hb * TT + t] = ss; tar_ws[hb * TT + t] = ts; }
    }
}

// ---------------- Kernel 2: masked softmax + att@h via bf16 MFMA, mean over heads
__global__ __launch_bounds__(256) void k2_attn(
        const unsigned short* __restrict__ hT, const float* __restrict__ src_ws,
        const float* __restrict__ tar_ws, float* __restrict__ msgs) {
    __shared__ float srcv[512];
    __shared__ float red[4];
    __shared__ float partial[4][64];
    __shared__ float drow[64];
    __shared__ __align__(16) unsigned short es[64 * 128];  // swizzled [t][s] bf16
    __shared__ __align__(16) unsigned short hs[64 * 128];  // swizzled [k][s] bf16

    const int t0 = blockIdx.x * 64;
    const int b  = blockIdx.y;
    const int hh = blockIdx.z;
    const int tid = threadIdx.x;
    const long hb = (long)hh * BB + b;
    const float* srcp = src_ws + hb * TT;

    for (int e = tid; e < 512; e += 256) srcv[e] = (e < TT) ? srcp[e] : -3.0e38f;
    __syncthreads();
    float sm = -3.0e38f;
    for (int e = tid; e < 512; e += 256) sm = fmaxf(sm, srcv[e]);
#pragma unroll
    for (int o = 32; o > 0; o >>= 1) sm = fmaxf(sm, __shfl_xor(sm, o));
    if ((tid & 63) == 0) red[tid >> 6] = sm;
    __syncthreads();
    const float Smax = fmaxf(fmaxf(red[0], red[1]), fmaxf(red[2], red[3]));

    const int tl = tid & 63, g = tid >> 6;
    const int tglob = t0 + tl;
    const float tv = (tglob < TT) ? tar_ws[hb * TT + tglob] : 0.f;
    // exact row max: leaky_relu is monotonic, so m_t = leaky(tar_t + max_s src_s)
    const float xm = tv + Smax;
    const float ml = fmaxf(xm, 0.2f * xm);

    const unsigned short* hTg = hT + hb * (64L * 512);
    const int lane = tid & 63, wid = tid >> 6;
    const int wr = wid >> 1, wc = wid & 1;
    f32x16 acc;
#pragma unroll
    for (int r = 0; r < 16; ++r) acc[r] = 0.f;

    float lsum = 0.f;
    for (int s0 = 0; s0 < 512; s0 += 128) {
        // stage h tile [64 k-rows][128 s] bf16, XOR-swizzled
#pragma unroll
        for (int p = 0; p < 4; ++p) {
            const int r = p * 16 + (tid >> 4), c = tid & 15;
            const int4 hv = *(const int4*)(hTg + (long)r * 512 + s0 + c * 8);
            const int wa = (r * 256 + c * 16) ^ ((r & 7) << 4);
            *(int4*)((char*)hs + wa) = hv;
        }
        // generate unnormalized e tile [64 t][128 s] bf16, XOR-swizzled; fuse row-sum
#pragma unroll
        for (int i = 0; i < 4; ++i) {
            const int sl = g * 8 + i * 32;
            const int sg = s0 + sl;
            union { unsigned short u[8]; int4 v; } pk;
#pragma unroll
            for (int j = 0; j < 8; ++j) {
                float x = tv + srcv[sg + j];
                float l = fmaxf(x, 0.2f * x);     // leaky_relu(x,0.2) == max(x,0.2x)
                float e = __expf(l - ml);         // s>=500: srcv=-3e38 -> e=0
                if (sg + j == tglob) e = 0.f;     // diagonal mask
                lsum += e;
                pk.u[j] = f2bf(e);
            }
            const int wa = (tl * 256 + sl * 2) ^ ((tl & 7) << 4);
            *(int4*)((char*)es + wa) = pk.v;
        }
        __syncthreads();
        // 32x32x16 bf16 MFMA: wave (wr,wc) owns out[wr*32+32][wc*32+32]
#pragma unroll
        for (int st = 0; st < 8; ++st) {
            const int sA = st * 16 + (lane >> 5) * 8;
            const int arow = wr * 32 + (lane & 31);
            const int brow = wc * 32 + (lane & 31);
            bf16x8 av = *(bf16x8*)((char*)es + ((arow * 256 + sA * 2) ^ ((arow & 7) << 4)));
            bf16x8 bv = *(bf16x8*)((char*)hs + ((brow * 256 + sA * 2) ^ ((brow & 7) << 4)));
            acc = __builtin_amdgcn_mfma_f32_32x32x16_bf16(av, bv, acc, 0, 0, 0);
        }
        __syncthreads();
    }
    partial[g][tl] = lsum;
    __syncthreads();
    if (tid < 64) {
        float s = partial[0][tid] + partial[1][tid] + partial[2][tid] + partial[3][tid];
        drow[tid] = 1.f / s;
    }
    __syncthreads();
#pragma unroll
    for (int r = 0; r < 16; ++r) {
        const int row = wr * 32 + (r & 3) + 8 * (r >> 2) + 4 * (lane >> 5);
        const int t = t0 + row;
        if (t < TT) {
            const float v = acc[r] * drow[row] * 0.125f;
            atomicAdd(&msgs[((long)b * TT + t) * KK + (wc * 32 + (lane & 31))], v);
        }
    }
}

// ---------------- Kernel 3: tanh + GRU gates + MLP, one wave per row ------
__global__ __launch_bounds__(256) void k3_gru(
        const float* __restrict__ inputs, const float* __restrict__ hidden,
        const float* __restrict__ bias,
        const float* __restrict__ W_hr, const float* __restrict__ W_hi, const float* __restrict__ W_hm,
        const float* __restrict__ W_ir, const float* __restrict__ b_ir,
        const float* __restrict__ W_ii, const float* __restrict__ b_ii,
        const float* __restrict__ W_in, const float* __restrict__ b_in,
        const float* __restrict__ W1, const float* __restrict__ b1,
        const float* __restrict__ W2, const float* __restrict__ b2,
        const float* __restrict__ msgs, float* __restrict__ out_hidden,
        float* __restrict__ pred) {
    const int tid = threadIdx.x;
    const int lane = tid & 63, w = tid >> 6;
    const int row = blockIdx.x * 4 + w;    // < 16000
    const float* inp = inputs + (long)row * DD;

    float mg = tanhf(msgs[(long)row * KK + lane] + bias[lane]);
    float hr = 0.f, hi = 0.f, hm = 0.f;
#pragma unroll 8
    for (int j = 0; j < KK; ++j) {
        float v = __shfl(mg, j);
        hr += v * W_hr[j * KK + lane];
        hi += v * W_hi[j * KK + lane];
        hm += v * W_hm[j * KK + lane];
    }
    float i0 = inp[lane], i1 = inp[64 + lane];
    float ir = 0.f, ii = 0.f, inn = 0.f;
#pragma unroll 8
    for (int j = 0; j < 64; ++j) {
        float v = __shfl(i0, j);
        ir  += v * W_ir[j * KK + lane];
        ii  += v * W_ii[j * KK + lane];
        inn += v * W_in[j * KK + lane];
    }
#pragma unroll 8
    for (int j = 0; j < 64; ++j) {
        float v = __shfl(i1, j);
        ir  += v * W_ir[(64 + j) * KK + lane];
        ii  += v * W_ii[(64 + j) * KK + lane];
        inn += v * W_in[(64 + j) * KK + lane];
    }
    float m  = 1.f / (1.f + expf(-(ir + b_ir[lane] + hr)));
    float ig = 1.f / (1.f + expf(-(ii + b_ii[lane] + hi)));
    float n  = tanhf(inn + b_in[lane] + m * hm);
    float hnew = ig * n + (1.f - ig) * hidden[(long)row * KK + lane];
    out_hidden[(long)row * KK + lane] = hnew;

    float a1 = 0.f;
#pragma unroll 8
    for (int j = 0; j < KK; ++j) a1 += __shfl(hnew, j) * W1[j * KK + lane];
    a1 = fmaxf(a1 + b1[lane], 0.f);
    float pr = 0.f;
#pragma unroll 8
    for (int j = 0; j < KK; ++j) pr += __shfl(a1, j) * W2[j * KK + lane];
    pred[(long)row * KK + lane] = pr + b2[lane];
}

// ---------------- Kernel 4: dargs = pred_resh @ proj_W  (LDS-broadcast GEMM)
// grid: x = 8 col-tiles (128 cols), y = 100 k-chunks (320 rows = 5 tiles of 64)
// per thread: 4b x 4c register tile; W staged f32 in LDS, P staged transposed+swizzled
__global__ __launch_bounds__(256) void k4_proj(
        const float* __restrict__ pred, const float* __restrict__ proj_W,
        float* __restrict__ dargs) {
    __shared__ __align__(16) float Wl[64 * 128];   // [r][c] 32KB
    __shared__ __align__(16) float Pl[64 * 32];    // [r][b] swizzled, 8KB
    const int tid = threadIdx.x;
    const int c0 = blockIdx.x * 128;
    const int r00 = blockIdx.y * 320;
    const int cg = tid & 31;        // col group: cols cg*4..cg*4+3
    const int bg = tid >> 5;        // b group:   b = bg*4..bg*4+3
    float acc[4][4];
#pragma unroll
    for (int i = 0; i < 4; ++i)
#pragma unroll
        for (int j = 0; j < 4; ++j) acc[i][j] = 0.f;

    for (int tile = 0; tile < 5; ++tile) {
        const int r0 = r00 + tile * 64;
        __syncthreads();
        // stage W[64][128] f32, coalesced float4
        {
            const int lr = tid >> 5;          // 0..7
            const int lc = (tid & 31) * 4;    // 0..124
            const int gc = c0 + lc;
#pragma unroll
            for (int p = 0; p < 8; ++p) {
                const int r = p * 8 + lr;
                float4 v = {0.f, 0.f, 0.f, 0.f};
                if (gc < 1000) v = *(const float4*)&proj_W[(long)(r0 + r) * 1000 + gc];
                *(float4*)&Wl[r * 128 + lc] = v;
            }
        }
        // stage P transposed: Pl[r][b] = pred[b][r0+r], XOR-swizzled rows
        {
            const int b = tid >> 3;           // 0..31
            const int q = tid & 7;            // 0..7
#pragma unroll
            for (int p = 0; p < 2; ++p) {
                const int rr = p * 32 + q * 4;
                const float4 v = *(const float4*)&pred[(long)b * 32000 + r00 + tile * 64 + rr];
                const float vv[4] = {v.x, v.y, v.z, v.w};
#pragma unroll
                for (int i = 0; i < 4; ++i) {
                    const int r = rr + i;
                    const int wa = (r * 128 + b * 4) ^ ((r & 7) << 4);
                    *(float*)((char*)Pl + wa) = vv[i];
                }
            }
        }
        __syncthreads();
#pragma unroll 4
        for (int r = 0; r < 64; ++r) {
            const float4 w = *(const float4*)&Wl[r * 128 + cg * 4];
            const float4 pv = *(const float4*)((const char*)Pl + ((r * 128 + bg * 16) ^ ((r & 7) << 4)));
            acc[0][0] += pv.x * w.x; acc[0][1] += pv.x * w.y; acc[0][2] += pv.x * w.z; acc[0][3] += pv.x * w.w;
            acc[1][0] += pv.y * w.x; acc[1][1] += pv.y * w.y; acc[1][2] += pv.y * w.z; acc[1][3] += pv.y * w.w;
            acc[2][0] += pv.z * w.x; acc[2][1] += pv.z * w.y; acc[2][2] += pv.z * w.z; acc[2][3] += pv.z * w.w;
            acc[3][0] += pv.w * w.x; acc[3][1] += pv.w * w.y; acc[3][2] += pv.w * w.z; acc[3][3] += pv.w * w.w;
        }
    }
    const int gc = c0 + cg * 4;
    if (gc < 1000) {
#pragma unroll
        for (int bi = 0; bi < 4; ++bi)
#pragma unroll
            for (int ci = 0; ci < 4; ++ci)
                atomicAdd(&dargs[(bg * 4 + bi) * 1000 + gc + ci], acc[bi][ci]);
    }
}

// ---------------- Kernel 5: + proj_b, split loc / softplus(scale) ---------
__global__ void k5_final(const float* __restrict__ dargs, const float* __restrict__ proj_b,
                         float* __restrict__ out) {
    int idx = blockIdx.x * 256 + threadIdx.x;
    if (idx >= BB * 1000) return;
    int b = idx / 1000, c = idx % 1000;
    float v = dargs[idx] + proj_b[c];
    if (c < TT) {
        out[b * TT + c] = v;                                  // loc
    } else {
        float sp = fmaxf(v, 0.f) + log1pf(expf(-fabsf(v)));   // softplus
        out[BB * TT + b * TT + (c - TT)] = sp;                // scale
    }
}

extern "C" void kernel_launch(void* const* d_in, const int* in_sizes, int n_in,
                              void* d_out, int out_size, void* d_ws, size_t ws_size,
                              hipStream_t stream) {
    const float* inputs  = (const float*)d_in[0];
    const float* hidden  = (const float*)d_in[1];
    const float* linear  = (const float*)d_in[2];
    const float* bias    = (const float*)d_in[3];
    const float* att_src = (const float*)d_in[4];
    const float* att_tar = (const float*)d_in[5];
    const float* W_hr = (const float*)d_in[6];
    const float* W_hi = (const float*)d_in[7];
    const float* W_hm = (const float*)d_in[8];
    const float* W_ir = (const float*)d_in[9];
    const float* b_ir = (const float*)d_in[10];
    const float* W_ii = (const float*)d_in[11];
    const float* b_ii = (const float*)d_in[12];
    const float* W_in = (const float*)d_in[13];
    const float* b_in = (const float*)d_in[14];
    const float* W1 = (const float*)d_in[15];
    const float* b1 = (const float*)d_in[16];
    const float* W2 = (const float*)d_in[17];
    const float* b2 = (const float*)d_in[18];
    const float* proj_W = (const float*)d_in[19];
    const float* proj_b = (const float*)d_in[20];

    unsigned short* hT = (unsigned short*)d_ws;             // H*B*64*512 bf16 = 8,388,608
    float* fbase  = (float*)(hT + 8388608);
    float* src_ws = fbase;                                  // 128,000
    float* tar_ws = src_ws + (size_t)HH * BB * TT;          // 128,000
    float* msgs   = tar_ws + (size_t)HH * BB * TT;          // 1,024,000
    float* pred   = msgs + (size_t)BB * TT * KK;            // 1,024,000
    float* dargs  = pred + (size_t)BB * TT * KK;            // 32,000

    float* out = (float*)d_out;
    float* out_hidden = out + 2 * BB * TT;

    hipMemsetAsync(msgs, 0, (size_t)BB * TT * KK * sizeof(float), stream);
    hipMemsetAsync(dargs, 0, (size_t)BB * 1000 * sizeof(float), stream);

    k1_h<<<dim3(8, BB, HH), 256, 0, stream>>>(inputs, linear, att_src, att_tar,
                                              hT, src_ws, tar_ws);
    k2_attn<<<dim3(8, BB, HH), 256, 0, stream>>>(hT, src_ws, tar_ws, msgs);
    k3_gru<<<4000, 256, 0, stream>>>(inputs, hidden, bias, W_hr, W_hi, W_hm,
                                     W_ir, b_ir, W_ii, b_ii, W_in, b_in,
                                     W1, b1, W2, b2, msgs, out_hidden, pred);
    k4_proj<<<dim3(8, 100), 256, 0, stream>>>(pred, proj_W, dargs);
    k5_final<<<125, 256, 0, stream>>>(dargs, proj_b, out);
}

// Round 6
// 501.365 us; speedup vs baseline: 1.7616x; 1.0731x over previous
//
#include <hip/hip_runtime.h>
#include <hip/hip_bf16.h>
#include <math.h>

// RGAT_Decoder: B=32,T=500,D=128,K=64,H=8.
// ws: hT bf16 [H*B][64][512] (16.78MB, ALIASED by part[125][32][1000] f32 16.0MB
//     after k2) | src_ws | tar_ws | msgs | pred | predT   (f32)
// total 30.1MB  (proven-safe budget >= 42.1MB from round 1)

#define BB 32
#define TT 500
#define DD 128
#define KK 64
#define HH 8

typedef short bf16x8 __attribute__((ext_vector_type(8)));
typedef float f32x16 __attribute__((ext_vector_type(16)));

static __device__ __forceinline__ unsigned short f2bf(float x) {
    __hip_bfloat16 h = __float2bfloat16(x);
    return *reinterpret_cast<unsigned short*>(&h);
}

// ---------------- Kernel 1: h = einsum('btd,hdk->hbtk') -> bf16 hT + src/tar dots
__global__ __launch_bounds__(256) void k1_h(
        const float* __restrict__ inputs, const float* __restrict__ linear,
        const float* __restrict__ att_src, const float* __restrict__ att_tar,
        unsigned short* __restrict__ hT, float* __restrict__ src_ws,
        float* __restrict__ tar_ws) {
    __shared__ __align__(16) float lin_s[DD * KK];   // [d][k]
    __shared__ __align__(16) float inp_s[64 * DD];   // [tl][d]
    __shared__ float asrc_s[KK], atar_s[KK];
    const int t0 = blockIdx.x * 64;
    const int b  = blockIdx.y;
    const int hh = blockIdx.z;
    const int tid = threadIdx.x;
    const int k = tid & 63, tq = tid >> 6;

    for (int e = tid; e < DD * KK; e += 256) lin_s[e] = linear[hh * DD * KK + e];
    for (int e = tid; e < 64 * DD; e += 256) {
        int row = e >> 7, d = e & 127;
        int t = t0 + row;
        inp_s[e] = (t < TT) ? inputs[(b * TT + t) * DD + d] : 0.f;
    }
    if (tid < KK) { asrc_s[tid] = att_src[hh * KK + tid]; atar_s[tid] = att_tar[hh * KK + tid]; }
    __syncthreads();

    float acc[16];
#pragma unroll
    for (int i = 0; i < 16; ++i) acc[i] = 0.f;

    for (int d4 = 0; d4 < DD / 4; ++d4) {
        float l0 = lin_s[(d4 * 4 + 0) * KK + k];
        float l1 = lin_s[(d4 * 4 + 1) * KK + k];
        float l2 = lin_s[(d4 * 4 + 2) * KK + k];
        float l3 = lin_s[(d4 * 4 + 3) * KK + k];
#pragma unroll
        for (int i = 0; i < 16; ++i) {
            const float4 iv = *(const float4*)&inp_s[(tq * 16 + i) * DD + d4 * 4];
            acc[i] += iv.x * l0 + iv.y * l1 + iv.z * l2 + iv.w * l3;
        }
    }
    const long hb = (long)hh * BB + b;
    // transposed bf16 store: hT[hb][k][t0 + tq*16 .. +16]  (rows t>=500 are exact 0)
    {
        union { unsigned short u[16]; int4 v[2]; } pk;
#pragma unroll
        for (int i = 0; i < 16; ++i) pk.u[i] = f2bf(acc[i]);
        unsigned short* hp = hT + hb * (64L * 512) + (long)k * 512 + t0 + tq * 16;
        *(int4*)(hp)     = pk.v[0];
        *(int4*)(hp + 8) = pk.v[1];
    }
    const float sv = asrc_s[k], tv = atar_s[k];
#pragma unroll
    for (int i = 0; i < 16; ++i) {
        float ss = acc[i] * sv, ts = acc[i] * tv;
#pragma unroll
        for (int o = 32; o > 0; o >>= 1) { ss += __shfl_xor(ss, o); ts += __shfl_xor(ts, o); }
        int t = t0 + tq * 16 + i;
        if (k == 0 && t < TT) { src_ws[hb * TT + t] = ss; tar_ws[hb * TT + t] = ts; }
    }
}

// ---------------- Kernel 2: masked softmax + att@h via bf16 MFMA, mean over heads
__global__ __launch_bounds__(256) void k2_attn(
        const unsigned short* __restrict__ hT, const float* __restrict__ src_ws,
        const float* __restrict__ tar_ws, float* __restrict__ msgs) {
    __shared__ float srcv[512];
    __shared__ float red[4];
    __shared__ float partial[4][64];
    __shared__ float drow[64];
    __shared__ __align__(16) unsigned short es[64 * 128];  // swizzled [t][s] bf16
    __shared__ __align__(16) unsigned short hs[64 * 128];  // swizzled [k][s] bf16

    const int t0 = blockIdx.x * 64;
    const int b  = blockIdx.y;
    const int hh = blockIdx.z;
    const int tid = threadIdx.x;
    const long hb = (long)hh * BB + b;
    const float* srcp = src_ws + hb * TT;

    for (int e = tid; e < 512; e += 256) srcv[e] = (e < TT) ? srcp[e] : -3.0e38f;
    __syncthreads();
    float sm = -3.0e38f;
    for (int e = tid; e < 512; e += 256) sm = fmaxf(sm, srcv[e]);
#pragma unroll
    for (int o = 32; o > 0; o >>= 1) sm = fmaxf(sm, __shfl_xor(sm, o));
    if ((tid & 63) == 0) red[tid >> 6] = sm;
    __syncthreads();
    const float Smax = fmaxf(fmaxf(red[0], red[1]), fmaxf(red[2], red[3]));

    const int tl = tid & 63, g = tid >> 6;
    const int tglob = t0 + tl;
    const float tv = (tglob < TT) ? tar_ws[hb * TT + tglob] : 0.f;
    // exact row max: leaky_relu is monotonic, so m_t = leaky(tar_t + max_s src_s)
    const float xm = tv + Smax;
    const float ml = fmaxf(xm, 0.2f * xm);

    const unsigned short* hTg = hT + hb * (64L * 512);
    const int lane = tid & 63, wid = tid >> 6;
    const int wr = wid >> 1, wc = wid & 1;
    f32x16 acc;
#pragma unroll
    for (int r = 0; r < 16; ++r) acc[r] = 0.f;

    float lsum = 0.f;
    for (int s0 = 0; s0 < 512; s0 += 128) {
        // stage h tile [64 k-rows][128 s] bf16, XOR-swizzled
#pragma unroll
        for (int p = 0; p < 4; ++p) {
            const int r = p * 16 + (tid >> 4), c = tid & 15;
            const int4 hv = *(const int4*)(hTg + (long)r * 512 + s0 + c * 8);
            const int wa = (r * 256 + c * 16) ^ ((r & 7) << 4);
            *(int4*)((char*)hs + wa) = hv;
        }
        // generate unnormalized e tile [64 t][128 s] bf16, XOR-swizzled; fuse row-sum
#pragma unroll
        for (int i = 0; i < 4; ++i) {
            const int sl = g * 8 + i * 32;
            const int sg = s0 + sl;
            union { unsigned short u[8]; int4 v; } pk;
#pragma unroll
            for (int j = 0; j < 8; ++j) {
                float x = tv + srcv[sg + j];
                float l = fmaxf(x, 0.2f * x);     // leaky_relu(x,0.2) == max(x,0.2x)
                float e = __expf(l - ml);         // s>=500: srcv=-3e38 -> e=0
                if (sg + j == tglob) e = 0.f;     // diagonal mask
                lsum += e;
                pk.u[j] = f2bf(e);
            }
            const int wa = (tl * 256 + sl * 2) ^ ((tl & 7) << 4);
            *(int4*)((char*)es + wa) = pk.v;
        }
        __syncthreads();
        // 32x32x16 bf16 MFMA: wave (wr,wc) owns out[wr*32+32][wc*32+32]
#pragma unroll
        for (int st = 0; st < 8; ++st) {
            const int sA = st * 16 + (lane >> 5) * 8;
            const int arow = wr * 32 + (lane & 31);
            const int brow = wc * 32 + (lane & 31);
            bf16x8 av = *(bf16x8*)((char*)es + ((arow * 256 + sA * 2) ^ ((arow & 7) << 4)));
            bf16x8 bv = *(bf16x8*)((char*)hs + ((brow * 256 + sA * 2) ^ ((brow & 7) << 4)));
            acc = __builtin_amdgcn_mfma_f32_32x32x16_bf16(av, bv, acc, 0, 0, 0);
        }
        __syncthreads();
    }
    partial[g][tl] = lsum;
    __syncthreads();
    if (tid < 64) {
        float s = partial[0][tid] + partial[1][tid] + partial[2][tid] + partial[3][tid];
        drow[tid] = 1.f / s;
    }
    __syncthreads();
#pragma unroll
    for (int r = 0; r < 16; ++r) {
        const int row = wr * 32 + (r & 3) + 8 * (r >> 2) + 4 * (lane >> 5);
        const int t = t0 + row;
        if (t < TT) {
            const float v = acc[r] * drow[row] * 0.125f;
            atomicAdd(&msgs[((long)b * TT + t) * KK + (wc * 32 + (lane & 31))], v);
        }
    }
}

// ---------------- Kernel 3: tanh + GRU gates + MLP, one wave per row ------
__global__ __launch_bounds__(256) void k3_gru(
        const float* __restrict__ inputs, const float* __restrict__ hidden,
        const float* __restrict__ bias,
        const float* __restrict__ W_hr, const float* __restrict__ W_hi, const float* __restrict__ W_hm,
        const float* __restrict__ W_ir, const float* __restrict__ b_ir,
        const float* __restrict__ W_ii, const float* __restrict__ b_ii,
        const float* __restrict__ W_in, const float* __restrict__ b_in,
        const float* __restrict__ W1, const float* __restrict__ b1,
        const float* __restrict__ W2, const float* __restrict__ b2,
        const float* __restrict__ msgs, float* __restrict__ out_hidden,
        float* __restrict__ pred) {
    const int tid = threadIdx.x;
    const int lane = tid & 63, w = tid >> 6;
    const int row = blockIdx.x * 4 + w;    // < 16000
    const float* inp = inputs + (long)row * DD;

    float mg = tanhf(msgs[(long)row * KK + lane] + bias[lane]);
    float hr = 0.f, hi = 0.f, hm = 0.f;
#pragma unroll 8
    for (int j = 0; j < KK; ++j) {
        float v = __shfl(mg, j);
        hr += v * W_hr[j * KK + lane];
        hi += v * W_hi[j * KK + lane];
        hm += v * W_hm[j * KK + lane];
    }
    float i0 = inp[lane], i1 = inp[64 + lane];
    float ir = 0.f, ii = 0.f, inn = 0.f;
#pragma unroll 8
    for (int j = 0; j < 64; ++j) {
        float v = __shfl(i0, j);
        ir  += v * W_ir[j * KK + lane];
        ii  += v * W_ii[j * KK + lane];
        inn += v * W_in[j * KK + lane];
    }
#pragma unroll 8
    for (int j = 0; j < 64; ++j) {
        float v = __shfl(i1, j);
        ir  += v * W_ir[(64 + j) * KK + lane];
        ii  += v * W_ii[(64 + j) * KK + lane];
        inn += v * W_in[(64 + j) * KK + lane];
    }
    float m  = 1.f / (1.f + expf(-(ir + b_ir[lane] + hr)));
    float ig = 1.f / (1.f + expf(-(ii + b_ii[lane] + hi)));
    float n  = tanhf(inn + b_in[lane] + m * hm);
    float hnew = ig * n + (1.f - ig) * hidden[(long)row * KK + lane];
    out_hidden[(long)row * KK + lane] = hnew;

    float a1 = 0.f;
#pragma unroll 8
    for (int j = 0; j < KK; ++j) a1 += __shfl(hnew, j) * W1[j * KK + lane];
    a1 = fmaxf(a1 + b1[lane], 0.f);
    float pr = 0.f;
#pragma unroll 8
    for (int j = 0; j < KK; ++j) pr += __shfl(a1, j) * W2[j * KK + lane];
    pred[(long)row * KK + lane] = pr + b2[lane];
}

// ---------------- Kernel 3b: transpose pred[32][32000] -> predT[32000][32] ----
__global__ __launch_bounds__(256) void k3b_transpose(
        const float* __restrict__ pred, float* __restrict__ predT) {
    __shared__ float Tl[64][36];                 // padded, 9.2KB
    const int r0 = blockIdx.x * 64;
    const int tid = threadIdx.x;
    {
        const int b = tid >> 3, q = tid & 7;     // b 0..31, q 0..7
        const float* pb = pred + (long)b * 32000 + r0;
#pragma unroll
        for (int j = 0; j < 2; ++j) {
            const int r = q * 8 + j * 4;
            const float4 v = *(const float4*)&pb[r];
            Tl[r + 0][b] = v.x; Tl[r + 1][b] = v.y;
            Tl[r + 2][b] = v.z; Tl[r + 3][b] = v.w;
        }
    }
    __syncthreads();
    {
        const int r = tid >> 2, bq = tid & 3;    // r 0..63, bq 0..3
        float* op = predT + (long)(r0 + r) * 32 + bq * 8;
        *(float4*)(op)     = *(const float4*)&Tl[r][bq * 8];
        *(float4*)(op + 4) = *(const float4*)&Tl[r][bq * 8 + 4];
    }
}

// ---------------- Kernel 4: part[y] = pred_chunk @ proj_W  (register streaming)
// grid (4, 125): block = 256 cols x 256 rows; wave w owns rows w*64..w*64+63.
// W streamed global->VGPR ring (no LDS, no barrier in main loop); P rows are
// wave-uniform (predT) -> scalar loads. Cross-wave reduce in LDS, no atomics.
#define FMA4(A, S, W) { (A).x += (S)*(W).x; (A).y += (S)*(W).y; (A).z += (S)*(W).z; (A).w += (S)*(W).w; }
__global__ __launch_bounds__(256) void k4_proj(
        const float* __restrict__ predT, const float* __restrict__ proj_W,
        float* __restrict__ part) {
    __shared__ float red[3][4096];               // 48KB
    const int tid = threadIdx.x;
    const int lane = tid & 63, w = tid >> 6;
    const int c = blockIdx.x * 256 + lane * 4;
    const bool cok = (c < 1000);
    const int r0w = blockIdx.y * 256 + w * 64;   // wave's global row base
    const int r0s = __builtin_amdgcn_readfirstlane(r0w);
    const float* pw = predT + (long)r0s * 32;
    const float* wp = proj_W + (long)r0w * 1000 + c;

    float4 acc[32];
#pragma unroll
    for (int b = 0; b < 32; ++b) acc[b] = float4{0.f, 0.f, 0.f, 0.f};

    const float4 f4z = {0.f, 0.f, 0.f, 0.f};
    float4 wbuf[4];
#pragma unroll
    for (int i = 0; i < 4; ++i)
        wbuf[i] = cok ? *(const float4*)&wp[(long)i * 1000] : f4z;

    for (int ch = 0; ch < 16; ++ch) {
#pragma unroll
        for (int i = 0; i < 4; ++i) {
            const int r = ch * 4 + i;
            const float4 wv = wbuf[i];
            const int rn = r + 4;
            if (rn < 64) wbuf[i] = cok ? *(const float4*)&wp[(long)rn * 1000] : f4z;
            const float* pr = pw + r * 32;
#pragma unroll
            for (int b4 = 0; b4 < 8; ++b4) {
                const float4 p4 = *(const float4*)&pr[b4 * 4];
                FMA4(acc[b4 * 4 + 0], p4.x, wv);
                FMA4(acc[b4 * 4 + 1], p4.y, wv);
                FMA4(acc[b4 * 4 + 2], p4.z, wv);
                FMA4(acc[b4 * 4 + 3], p4.w, wv);
            }
        }
    }
    // cross-wave reduction, 2 half-rounds of 16 b each; conflict-free layout
#pragma unroll
    for (int half = 0; half < 2; ++half) {
        const int bs = half * 16;
        if (w > 0) {
#pragma unroll
            for (int b = 0; b < 16; ++b) {
                red[w - 1][(b * 4 + 0) * 64 + lane] = acc[bs + b].x;
                red[w - 1][(b * 4 + 1) * 64 + lane] = acc[bs + b].y;
                red[w - 1][(b * 4 + 2) * 64 + lane] = acc[bs + b].z;
                red[w - 1][(b * 4 + 3) * 64 + lane] = acc[bs + b].w;
            }
        }
        __syncthreads();
        if (w == 0) {
#pragma unroll
            for (int b = 0; b < 16; ++b) {
                acc[bs + b].x += red[0][(b*4+0)*64+lane] + red[1][(b*4+0)*64+lane] + red[2][(b*4+0)*64+lane];
                acc[bs + b].y += red[0][(b*4+1)*64+lane] + red[1][(b*4+1)*64+lane] + red[2][(b*4+1)*64+lane];
                acc[bs + b].z += red[0][(b*4+2)*64+lane] + red[1][(b*4+2)*64+lane] + red[2][(b*4+2)*64+lane];
                acc[bs + b].w += red[0][(b*4+3)*64+lane] + red[1][(b*4+3)*64+lane] + red[2][(b*4+3)*64+lane];
            }
        }
        __syncthreads();
    }
    if (w == 0 && cok) {
#pragma unroll
        for (int b = 0; b < 32; ++b)
            *(float4*)&part[((long)blockIdx.y * 32 + b) * 1000 + c] = acc[b];
    }
}

// ---------------- Kernel 5: reduce 125 partials + proj_b, loc / softplus(scale)
__global__ __launch_bounds__(256) void k5_final(
        const float* __restrict__ part, const float* __restrict__ proj_b,
        float* __restrict__ out) {
    const int idx = blockIdx.x * 256 + threadIdx.x;   // 0..31999
    float v = 0.f;
    for (int y = 0; y < 125; ++y) v += part[(long)y * 32000 + idx];
    const int b = idx / 1000, cc = idx % 1000;
    v += proj_b[cc];
    if (cc < TT) {
        out[b * TT + cc] = v;                                 // loc
    } else {
        float sp = fmaxf(v, 0.f) + log1pf(expf(-fabsf(v)));   // softplus
        out[BB * TT + b * TT + (cc - TT)] = sp;               // scale
    }
}

extern "C" void kernel_launch(void* const* d_in, const int* in_sizes, int n_in,
                              void* d_out, int out_size, void* d_ws, size_t ws_size,
                              hipStream_t stream) {
    const float* inputs  = (const float*)d_in[0];
    const float* hidden  = (const float*)d_in[1];
    const float* linear  = (const float*)d_in[2];
    const float* bias    = (const float*)d_in[3];
    const float* att_src = (const float*)d_in[4];
    const float* att_tar = (const float*)d_in[5];
    const float* W_hr = (const float*)d_in[6];
    const float* W_hi = (const float*)d_in[7];
    const float* W_hm = (const float*)d_in[8];
    const float* W_ir = (const float*)d_in[9];
    const float* b_ir = (const float*)d_in[10];
    const float* W_ii = (const float*)d_in[11];
    const float* b_ii = (const float*)d_in[12];
    const float* W_in = (const float*)d_in[13];
    const float* b_in = (const float*)d_in[14];
    const float* W1 = (const float*)d_in[15];
    const float* b1 = (const float*)d_in[16];
    const float* W2 = (const float*)d_in[17];
    const float* b2 = (const float*)d_in[18];
    const float* proj_W = (const float*)d_in[19];
    const float* proj_b = (const float*)d_in[20];

    unsigned short* hT = (unsigned short*)d_ws;        // 16,777,216 B
    float* part = (float*)d_ws;                        // ALIAS of hT region (16.0MB),
                                                       // live only after k2 consumed hT
    float* fbase  = (float*)(hT + 8388608);
    float* src_ws = fbase;                             // 128,000 f32
    float* tar_ws = src_ws + (size_t)HH * BB * TT;     // 128,000
    float* msgs   = tar_ws + (size_t)HH * BB * TT;     // 1,024,000
    float* pred   = msgs + (size_t)BB * TT * KK;       // 1,024,000
    float* predT  = pred + (size_t)BB * TT * KK;       // 1,024,000

    float* out = (float*)d_out;
    float* out_hidden = out + 2 * BB * TT;

    hipMemsetAsync(msgs, 0, (size_t)BB * TT * KK * sizeof(float), stream);

    k1_h<<<dim3(8, BB, HH), 256, 0, stream>>>(inputs, linear, att_src, att_tar,
                                              hT, src_ws, tar_ws);
    k2_attn<<<dim3(8, BB, HH), 256, 0, stream>>>(hT, src_ws, tar_ws, msgs);
    k3_gru<<<4000, 256, 0, stream>>>(inputs, hidden, bias, W_hr, W_hi, W_hm,
                                     W_ir, b_ir, W_ii, b_ii, W_in, b_in,
                                     W1, b1, W2, b2, msgs, out_hidden, pred);
    k3b_transpose<<<500, 256, 0, stream>>>(pred, predT);
    k4_proj<<<dim3(4, 125), 256, 0, stream>>>(predT, proj_W, part);
    k5_final<<<125, 256, 0, stream>>>(part, proj_b, out);
}

// Round 7
// 419.900 us; speedup vs baseline: 2.1034x; 1.1940x over previous
//
#include <hip/hip_runtime.h>
#include <hip/hip_bf16.h>
#include <math.h>

// RGAT_Decoder: B=32,T=500,D=128,K=64,H=8.
// ws: hT bf16 [H*B][64][512] (16.78MB, ALIASED by part[125][32][1000] f32 16.0MB
//     after k2) | src_ws | tar_ws | msgs | pred | predT (f32) | linT (bf16 128KB)

#define BB 32
#define TT 500
#define DD 128
#define KK 64
#define HH 8

typedef short bf16x8 __attribute__((ext_vector_type(8)));
typedef float f32x16 __attribute__((ext_vector_type(16)));

static __device__ __forceinline__ unsigned short f2bf(float x) {
    __hip_bfloat16 h = __float2bfloat16(x);
    return *reinterpret_cast<unsigned short*>(&h);
}

// ---------------- Kernel 0: linT[h][k][d] bf16 <- linear[h][d][k] f32 (one-time)
__global__ __launch_bounds__(256) void k0_linT(
        const float* __restrict__ linear, unsigned short* __restrict__ linT) {
    const int h  = blockIdx.x >> 3;
    const int kb = (blockIdx.x & 7) * 8;
    const int kk = threadIdx.x >> 5;          // 0..7
    const int d0 = (threadIdx.x & 31) * 4;    // 0..124
    const float* lp = linear + (long)h * 8192 + (long)d0 * 64 + (kb + kk);
    union { unsigned short u[4]; int2 v; } o;
#pragma unroll
    for (int j = 0; j < 4; ++j) o.u[j] = f2bf(lp[(long)j * 64]);
    *(int2*)&linT[(long)h * 8192 + (kb + kk) * 128 + d0] = o.v;
}

// ---------------- Kernel 1: hT = bf16 MFMA einsum + src/tar dots ----------
__global__ __launch_bounds__(256) void k1_h(
        const float* __restrict__ inputs, const unsigned short* __restrict__ linT,
        const float* __restrict__ att_src, const float* __restrict__ att_tar,
        unsigned short* __restrict__ hT, float* __restrict__ src_ws,
        float* __restrict__ tar_ws) {
    __shared__ __align__(16) unsigned short inp_s[64 * 128];  // [t][d] bf16 swz
    __shared__ __align__(16) unsigned short lin_s[64 * 128];  // [k][d] bf16 swz
    __shared__ float asrc_s[KK], atar_s[KK];
    __shared__ float sred[2][64], tred[2][64];
    const int t0 = blockIdx.x * 64;
    const int b  = blockIdx.y;
    const int hh = blockIdx.z;
    const int tid = threadIdx.x;
    const int lane = tid & 63, wid = tid >> 6;
    const int wr = wid >> 1, wc = wid & 1;
    const long hb = (long)hh * BB + b;

    {   // stage inputs tile [64t][128d] -> bf16 swizzled (t>=500 rows zero)
        const int r = tid >> 2, q = tid & 3;
        const int t = t0 + r;
        union { unsigned short u[8]; int4 v; } pk;
#pragma unroll
        for (int j = 0; j < 4; ++j) {
            const int d0 = q * 32 + j * 8;
            if (t < TT) {
                const float4 a = *(const float4*)&inputs[((long)b * TT + t) * DD + d0];
                const float4 c = *(const float4*)&inputs[((long)b * TT + t) * DD + d0 + 4];
                pk.u[0] = f2bf(a.x); pk.u[1] = f2bf(a.y); pk.u[2] = f2bf(a.z); pk.u[3] = f2bf(a.w);
                pk.u[4] = f2bf(c.x); pk.u[5] = f2bf(c.y); pk.u[6] = f2bf(c.z); pk.u[7] = f2bf(c.w);
            } else {
                pk.v = int4{0, 0, 0, 0};
            }
            *(int4*)((char*)inp_s + ((r * 256 + d0 * 2) ^ ((r & 7) << 4))) = pk.v;
        }
    }
    {   // stage linT[hh] [64k][128d] bf16 -> swizzled
        const int r = tid >> 2, q = tid & 3;
        const unsigned short* lp = linT + (long)hh * 8192 + r * 128 + q * 32;
#pragma unroll
        for (int j = 0; j < 4; ++j) {
            const int d0 = q * 32 + j * 8;
            *(int4*)((char*)lin_s + ((r * 256 + d0 * 2) ^ ((r & 7) << 4))) =
                *(const int4*)(lp + j * 8);
        }
    }
    if (tid < KK) { asrc_s[tid] = att_src[hh * KK + tid]; atar_s[tid] = att_tar[hh * KK + tid]; }
    __syncthreads();

    f32x16 acc;
#pragma unroll
    for (int r = 0; r < 16; ++r) acc[r] = 0.f;
#pragma unroll
    for (int st = 0; st < 8; ++st) {
        const int sA = st * 16 + (lane >> 5) * 8;
        const int arow = wr * 32 + (lane & 31);   // k row
        const int brow = wc * 32 + (lane & 31);   // t row
        bf16x8 av = *(bf16x8*)((char*)lin_s + ((arow * 256 + sA * 2) ^ ((arow & 7) << 4)));
        bf16x8 bv = *(bf16x8*)((char*)inp_s + ((brow * 256 + sA * 2) ^ ((brow & 7) << 4)));
        acc = __builtin_amdgcn_mfma_f32_32x32x16_bf16(av, bv, acc, 0, 0, 0);
    }
    // epilogue: hT store (coalesced 64B runs) + src/tar dots from f32 acc
    float sp = 0.f, tp = 0.f;
    unsigned short* hp = hT + hb * (64L * 512);
    const int tcol = t0 + wc * 32 + (lane & 31);
#pragma unroll
    for (int r = 0; r < 16; ++r) {
        const int kk = wr * 32 + (r & 3) + 8 * (r >> 2) + 4 * (lane >> 5);
        hp[(long)kk * 512 + tcol] = f2bf(acc[r]);
        sp += acc[r] * asrc_s[kk];
        tp += acc[r] * atar_s[kk];
    }
    sp += __shfl_xor(sp, 32);
    tp += __shfl_xor(tp, 32);
    if (lane < 32) { sred[wr][wc * 32 + lane] = sp; tred[wr][wc * 32 + lane] = tp; }
    __syncthreads();
    if (tid < 64) {
        const int t = t0 + tid;
        if (t < TT) {
            src_ws[hb * TT + t] = sred[0][tid] + sred[1][tid];
            tar_ws[hb * TT + t] = tred[0][tid] + tred[1][tid];
        }
    }
}

// ---------------- Kernel 2: masked softmax + att@h via bf16 MFMA, mean over heads
__global__ __launch_bounds__(256) void k2_attn(
        const unsigned short* __restrict__ hT, const float* __restrict__ src_ws,
        const float* __restrict__ tar_ws, float* __restrict__ msgs) {
    __shared__ float srcv[512];
    __shared__ float red[4];
    __shared__ float partial[4][64];
    __shared__ float drow[64];
    __shared__ __align__(16) unsigned short es[64 * 128];  // swizzled [t][s] bf16
    __shared__ __align__(16) unsigned short hs[64 * 128];  // swizzled [k][s] bf16

    const int t0 = blockIdx.x * 64;
    const int b  = blockIdx.y;
    const int hh = blockIdx.z;
    const int tid = threadIdx.x;
    const long hb = (long)hh * BB + b;
    const float* srcp = src_ws + hb * TT;

    for (int e = tid; e < 512; e += 256) srcv[e] = (e < TT) ? srcp[e] : -3.0e38f;
    __syncthreads();
    float sm = -3.0e38f;
    for (int e = tid; e < 512; e += 256) sm = fmaxf(sm, srcv[e]);
#pragma unroll
    for (int o = 32; o > 0; o >>= 1) sm = fmaxf(sm, __shfl_xor(sm, o));
    if ((tid & 63) == 0) red[tid >> 6] = sm;
    __syncthreads();
    const float Smax = fmaxf(fmaxf(red[0], red[1]), fmaxf(red[2], red[3]));

    const int tl = tid & 63, g = tid >> 6;
    const int tglob = t0 + tl;
    const float tv = (tglob < TT) ? tar_ws[hb * TT + tglob] : 0.f;
    // exact row max: leaky_relu is monotonic, so m_t = leaky(tar_t + max_s src_s)
    const float xm = tv + Smax;
    const float ml = fmaxf(xm, 0.2f * xm);

    const unsigned short* hTg = hT + hb * (64L * 512);
    const int lane = tid & 63, wid = tid >> 6;
    const int wr = wid >> 1, wc = wid & 1;
    f32x16 acc;
#pragma unroll
    for (int r = 0; r < 16; ++r) acc[r] = 0.f;

    float lsum = 0.f;
    for (int s0 = 0; s0 < 512; s0 += 128) {
        // stage h tile [64 k-rows][128 s] bf16, XOR-swizzled
#pragma unroll
        for (int p = 0; p < 4; ++p) {
            const int r = p * 16 + (tid >> 4), c = tid & 15;
            const int4 hv = *(const int4*)(hTg + (long)r * 512 + s0 + c * 8);
            const int wa = (r * 256 + c * 16) ^ ((r & 7) << 4);
            *(int4*)((char*)hs + wa) = hv;
        }
        // generate unnormalized e tile [64 t][128 s] bf16, XOR-swizzled; fuse row-sum
#pragma unroll
        for (int i = 0; i < 4; ++i) {
            const int sl = g * 8 + i * 32;
            const int sg = s0 + sl;
            union { unsigned short u[8]; int4 v; } pk;
#pragma unroll
            for (int j = 0; j < 8; ++j) {
                float x = tv + srcv[sg + j];
                float l = fmaxf(x, 0.2f * x);     // leaky_relu(x,0.2) == max(x,0.2x)
                float e = __expf(l - ml);         // s>=500: srcv=-3e38 -> e=0
                if (sg + j == tglob) e = 0.f;     // diagonal mask
                lsum += e;
                pk.u[j] = f2bf(e);
            }
            const int wa = (tl * 256 + sl * 2) ^ ((tl & 7) << 4);
            *(int4*)((char*)es + wa) = pk.v;
        }
        __syncthreads();
        // 32x32x16 bf16 MFMA: wave (wr,wc) owns out[wr*32+32][wc*32+32]
#pragma unroll
        for (int st = 0; st < 8; ++st) {
            const int sA = st * 16 + (lane >> 5) * 8;
            const int arow = wr * 32 + (lane & 31);
            const int brow = wc * 32 + (lane & 31);
            bf16x8 av = *(bf16x8*)((char*)es + ((arow * 256 + sA * 2) ^ ((arow & 7) << 4)));
            bf16x8 bv = *(bf16x8*)((char*)hs + ((brow * 256 + sA * 2) ^ ((brow & 7) << 4)));
            acc = __builtin_amdgcn_mfma_f32_32x32x16_bf16(av, bv, acc, 0, 0, 0);
        }
        __syncthreads();
    }
    partial[g][tl] = lsum;
    __syncthreads();
    if (tid < 64) {
        float s = partial[0][tid] + partial[1][tid] + partial[2][tid] + partial[3][tid];
        drow[tid] = 1.f / s;
    }
    __syncthreads();
#pragma unroll
    for (int r = 0; r < 16; ++r) {
        const int row = wr * 32 + (r & 3) + 8 * (r >> 2) + 4 * (lane >> 5);
        const int t = t0 + row;
        if (t < TT) {
            const float v = acc[r] * drow[row] * 0.125f;
            atomicAdd(&msgs[((long)b * TT + t) * KK + (wc * 32 + (lane & 31))], v);
        }
    }
}

// ---------------- Kernel 3: tanh + GRU gates + MLP, one wave per row ------
__global__ __launch_bounds__(256) void k3_gru(
        const float* __restrict__ inputs, const float* __restrict__ hidden,
        const float* __restrict__ bias,
        const float* __restrict__ W_hr, const float* __restrict__ W_hi, const float* __restrict__ W_hm,
        const float* __restrict__ W_ir, const float* __restrict__ b_ir,
        const float* __restrict__ W_ii, const float* __restrict__ b_ii,
        const float* __restrict__ W_in, const float* __restrict__ b_in,
        const float* __restrict__ W1, const float* __restrict__ b1,
        const float* __restrict__ W2, const float* __restrict__ b2,
        const float* __restrict__ msgs, float* __restrict__ out_hidden,
        float* __restrict__ pred) {
    const int tid = threadIdx.x;
    const int lane = tid & 63, w = tid >> 6;
    const int row = blockIdx.x * 4 + w;    // < 16000
    const float* inp = inputs + (long)row * DD;

    float mg = tanhf(msgs[(long)row * KK + lane] + bias[lane]);
    float hr = 0.f, hi = 0.f, hm = 0.f;
#pragma unroll 8
    for (int j = 0; j < KK; ++j) {
        float v = __shfl(mg, j);
        hr += v * W_hr[j * KK + lane];
        hi += v * W_hi[j * KK + lane];
        hm += v * W_hm[j * KK + lane];
    }
    float i0 = inp[lane], i1 = inp[64 + lane];
    float ir = 0.f, ii = 0.f, inn = 0.f;
#pragma unroll 8
    for (int j = 0; j < 64; ++j) {
        float v = __shfl(i0, j);
        ir  += v * W_ir[j * KK + lane];
        ii  += v * W_ii[j * KK + lane];
        inn += v * W_in[j * KK + lane];
    }
#pragma unroll 8
    for (int j = 0; j < 64; ++j) {
        float v = __shfl(i1, j);
        ir  += v * W_ir[(64 + j) * KK + lane];
        ii  += v * W_ii[(64 + j) * KK + lane];
        inn += v * W_in[(64 + j) * KK + lane];
    }
    float m  = 1.f / (1.f + expf(-(ir + b_ir[lane] + hr)));
    float ig = 1.f / (1.f + expf(-(ii + b_ii[lane] + hi)));
    float n  = tanhf(inn + b_in[lane] + m * hm);
    float hnew = ig * n + (1.f - ig) * hidden[(long)row * KK + lane];
    out_hidden[(long)row * KK + lane] = hnew;

    float a1 = 0.f;
#pragma unroll 8
    for (int j = 0; j < KK; ++j) a1 += __shfl(hnew, j) * W1[j * KK + lane];
    a1 = fmaxf(a1 + b1[lane], 0.f);
    float pr = 0.f;
#pragma unroll 8
    for (int j = 0; j < KK; ++j) pr += __shfl(a1, j) * W2[j * KK + lane];
    pred[(long)row * KK + lane] = pr + b2[lane];
}

// ---------------- Kernel 3b: transpose pred[32][32000] -> predT[32000][32] ----
__global__ __launch_bounds__(256) void k3b_transpose(
        const float* __restrict__ pred, float* __restrict__ predT) {
    __shared__ float Tl[64][36];                 // padded, 9.2KB
    const int r0 = blockIdx.x * 64;
    const int tid = threadIdx.x;
    {
        const int b = tid >> 3, q = tid & 7;     // b 0..31, q 0..7
        const float* pb = pred + (long)b * 32000 + r0;
#pragma unroll
        for (int j = 0; j < 2; ++j) {
            const int r = q * 8 + j * 4;
            const float4 v = *(const float4*)&pb[r];
            Tl[r + 0][b] = v.x; Tl[r + 1][b] = v.y;
            Tl[r + 2][b] = v.z; Tl[r + 3][b] = v.w;
        }
    }
    __syncthreads();
    {
        const int r = tid >> 2, bq = tid & 3;    // r 0..63, bq 0..3
        float* op = predT + (long)(r0 + r) * 32 + bq * 8;
        *(float4*)(op)     = *(const float4*)&Tl[r][bq * 8];
        *(float4*)(op + 4) = *(const float4*)&Tl[r][bq * 8 + 4];
    }
}

// ---------------- Kernel 4: part[y] = pred_chunk @ proj_W  (register streaming)
#define FMA4(A, S, W) { (A).x += (S)*(W).x; (A).y += (S)*(W).y; (A).z += (S)*(W).z; (A).w += (S)*(W).w; }
__global__ __launch_bounds__(256) void k4_proj(
        const float* __restrict__ predT, const float* __restrict__ proj_W,
        float* __restrict__ part) {
    __shared__ float red[3][4096];               // 48KB
    const int tid = threadIdx.x;
    const int lane = tid & 63, w = tid >> 6;
    const int c = blockIdx.x * 256 + lane * 4;
    const bool cok = (c < 1000);
    const int r0w = blockIdx.y * 256 + w * 64;   // wave's global row base
    const int r0s = __builtin_amdgcn_readfirstlane(r0w);
    const float* pw = predT + (long)r0s * 32;
    const float* wp = proj_W + (long)r0w * 1000 + c;

    float4 acc[32];
#pragma unroll
    for (int b = 0; b < 32; ++b) acc[b] = float4{0.f, 0.f, 0.f, 0.f};

    const float4 f4z = {0.f, 0.f, 0.f, 0.f};
    float4 wbuf[4];
#pragma unroll
    for (int i = 0; i < 4; ++i)
        wbuf[i] = cok ? *(const float4*)&wp[(long)i * 1000] : f4z;

    for (int ch = 0; ch < 16; ++ch) {
#pragma unroll
        for (int i = 0; i < 4; ++i) {
            const int r = ch * 4 + i;
            const float4 wv = wbuf[i];
            const int rn = r + 4;
            if (rn < 64) wbuf[i] = cok ? *(const float4*)&wp[(long)rn * 1000] : f4z;
            const float* pr = pw + r * 32;
#pragma unroll
            for (int b4 = 0; b4 < 8; ++b4) {
                const float4 p4 = *(const float4*)&pr[b4 * 4];
                FMA4(acc[b4 * 4 + 0], p4.x, wv);
                FMA4(acc[b4 * 4 + 1], p4.y, wv);
                FMA4(acc[b4 * 4 + 2], p4.z, wv);
                FMA4(acc[b4 * 4 + 3], p4.w, wv);
            }
        }
    }
    // cross-wave reduction, 2 half-rounds of 16 b each; conflict-free layout
#pragma unroll
    for (int half = 0; half < 2; ++half) {
        const int bs = half * 16;
        if (w > 0) {
#pragma unroll
            for (int b = 0; b < 16; ++b) {
                red[w - 1][(b * 4 + 0) * 64 + lane] = acc[bs + b].x;
                red[w - 1][(b * 4 + 1) * 64 + lane] = acc[bs + b].y;
                red[w - 1][(b * 4 + 2) * 64 + lane] = acc[bs + b].z;
                red[w - 1][(b * 4 + 3) * 64 + lane] = acc[bs + b].w;
            }
        }
        __syncthreads();
        if (w == 0) {
#pragma unroll
            for (int b = 0; b < 16; ++b) {
                acc[bs + b].x += red[0][(b*4+0)*64+lane] + red[1][(b*4+0)*64+lane] + red[2][(b*4+0)*64+lane];
                acc[bs + b].y += red[0][(b*4+1)*64+lane] + red[1][(b*4+1)*64+lane] + red[2][(b*4+1)*64+lane];
                acc[bs + b].z += red[0][(b*4+2)*64+lane] + red[1][(b*4+2)*64+lane] + red[2][(b*4+2)*64+lane];
                acc[bs + b].w += red[0][(b*4+3)*64+lane] + red[1][(b*4+3)*64+lane] + red[2][(b*4+3)*64+lane];
            }
        }
        __syncthreads();
    }
    if (w == 0 && cok) {
#pragma unroll
        for (int b = 0; b < 32; ++b)
            *(float4*)&part[((long)blockIdx.y * 32 + b) * 1000 + c] = acc[b];
    }
}

// ---------------- Kernel 5: reduce 125 partials + proj_b, loc / softplus(scale)
__global__ __launch_bounds__(256) void k5_final(
        const float* __restrict__ part, const float* __restrict__ proj_b,
        float* __restrict__ out) {
    const int idx = blockIdx.x * 256 + threadIdx.x;   // 0..31999
    float v = 0.f;
    for (int y = 0; y < 125; ++y) v += part[(long)y * 32000 + idx];
    const int b = idx / 1000, cc = idx % 1000;
    v += proj_b[cc];
    if (cc < TT) {
        out[b * TT + cc] = v;                                 // loc
    } else {
        float sp = fmaxf(v, 0.f) + log1pf(expf(-fabsf(v)));   // softplus
        out[BB * TT + b * TT + (cc - TT)] = sp;               // scale
    }
}

extern "C" void kernel_launch(void* const* d_in, const int* in_sizes, int n_in,
                              void* d_out, int out_size, void* d_ws, size_t ws_size,
                              hipStream_t stream) {
    const float* inputs  = (const float*)d_in[0];
    const float* hidden  = (const float*)d_in[1];
    const float* linear  = (const float*)d_in[2];
    const float* bias    = (const float*)d_in[3];
    const float* att_src = (const float*)d_in[4];
    const float* att_tar = (const float*)d_in[5];
    const float* W_hr = (const float*)d_in[6];
    const float* W_hi = (const float*)d_in[7];
    const float* W_hm = (const float*)d_in[8];
    const float* W_ir = (const float*)d_in[9];
    const float* b_ir = (const float*)d_in[10];
    const float* W_ii = (const float*)d_in[11];
    const float* b_ii = (const float*)d_in[12];
    const float* W_in = (const float*)d_in[13];
    const float* b_in = (const float*)d_in[14];
    const float* W1 = (const float*)d_in[15];
    const float* b1 = (const float*)d_in[16];
    const float* W2 = (const float*)d_in[17];
    const float* b2 = (const float*)d_in[18];
    const float* proj_W = (const float*)d_in[19];
    const float* proj_b = (const float*)d_in[20];

    unsigned short* hT = (unsigned short*)d_ws;        // 16,777,216 B
    float* part = (float*)d_ws;                        // ALIAS of hT region (16.0MB),
                                                       // live only after k2 consumed hT
    float* fbase  = (float*)(hT + 8388608);
    float* src_ws = fbase;                             // 128,000 f32
    float* tar_ws = src_ws + (size_t)HH * BB * TT;     // 128,000
    float* msgs   = tar_ws + (size_t)HH * BB * TT;     // 1,024,000
    float* pred   = msgs + (size_t)BB * TT * KK;       // 1,024,000
    float* predT  = pred + (size_t)BB * TT * KK;       // 1,024,000
    unsigned short* linT = (unsigned short*)(predT + (size_t)BB * TT * KK); // 65,536 bf16

    float* out = (float*)d_out;
    float* out_hidden = out + 2 * BB * TT;

    hipMemsetAsync(msgs, 0, (size_t)BB * TT * KK * sizeof(float), stream);

    k0_linT<<<64, 256, 0, stream>>>(linear, linT);
    k1_h<<<dim3(8, BB, HH), 256, 0, stream>>>(inputs, linT, att_src, att_tar,
                                              hT, src_ws, tar_ws);
    k2_attn<<<dim3(8, BB, HH), 256, 0, stream>>>(hT, src_ws, tar_ws, msgs);
    k3_gru<<<4000, 256, 0, stream>>>(inputs, hidden, bias, W_hr, W_hi, W_hm,
                                     W_ir, b_ir, W_ii, b_ii, W_in, b_in,
                                     W1, b1, W2, b2, msgs, out_hidden, pred);
    k3b_transpose<<<500, 256, 0, stream>>>(pred, predT);
    k4_proj<<<dim3(4, 125), 256, 0, stream>>>(predT, proj_W, part);
    k5_final<<<125, 256, 0, stream>>>(part, proj_b, out);
}